// Round 2
// baseline (470.479 us; speedup 1.0000x reference)
//
#include <hip/hip_runtime.h>
#include <math.h>

// Problem constants (from reference)
#define K_SHEET   0.01f
#define K_CHAN    0.1f
#define CAV_SPACE 2.0f
#define FLOW_EXP  1.25f

// DISS = (1/917 - 1/1000)/3.34e5, computed in double, truncated to f32 (matches jnp)
__device__ __constant__ float c_diss = (float)((1.0 / 917.0 - 1.0 / 1000.0) / 3.34e5);

// One 256-thread block per matrix row. Thread 0 computes the row's <=5
// (col,val) nonzero pairs into LDS; then all threads stream the whole row
// to global as float4 zeros, substituting the nonzeros inline.
// This fuses the 400 MB zero-fill (the roofline) with the sparse patch.
__global__ __launch_bounds__(256) void sgds_row_kernel(
        const float* __restrict__ pot,          // [N]
        const float* __restrict__ chan,         // [L]
        const float* __restrict__ sheet,        // [N]
        const float* __restrict__ face_len,     // [L]
        const float* __restrict__ link_len,     // [L]
        const int*   __restrict__ adj,          // [N,4]
        const int*   __restrict__ lnk,          // [N,4]
        const int*   __restrict__ face_at_link, // [L]
        const int*   __restrict__ head,         // [L]
        const int*   __restrict__ tail,         // [L]
        const int*   __restrict__ inout,        // [N]
        float*       __restrict__ M,            // [N,N]
        int N)
{
    __shared__ int   s_col[8];
    __shared__ float s_val[8];
    __shared__ int   s_cnt;

    const int i = blockIdx.x;            // row id == node id
    float* row = M + (size_t)i * (size_t)N;

    if (threadIdx.x == 0) {
        int cnt = 0;
        if (inout[i] == 1) {
            // Dirichlet row: identity
            s_col[0] = i; s_val[0] = 1.0f; cnt = 1;
        } else {
            float diag = 0.0f;
            #pragma unroll
            for (int s = 0; s < 4; ++s) {
                int j = adj[i * 4 + s];
                if (j < 0) continue;                    // masked slot -> no contribution
                int lid = lnk[i * 4 + s];

                int   h  = head[lid];
                int   t  = tail[lid];
                float ll = link_len[lid];
                float g  = (pot[h] - pot[t]) / ll;       // grad[lid]

                float cq  = -K_CHAN * powf(chan[lid], FLOW_EXP) * g;        // chan_q
                float stl = 0.5f * (sheet[h] + sheet[t]);
                float gis = 1.0f / sqrtf(fabsf(g));                          // |g|^-0.5
                float sq  = -K_SHEET * powf(stl, FLOW_EXP) * gis * g;        // sheet_q

                float fl = face_len[face_at_link[lid]];
                // NOTE: reference indexes channel_size (link field) by NODE ids — faithful.
                float cs = 0.5f * (chan[i] + chan[j]);
                float st = 0.5f * (sheet[i] + sheet[j]);

                float sheet_flux = -K_SHEET * powf(st, FLOW_EXP) * gis * fl / ll;
                float chan_flux  = -K_CHAN  * powf(cs, FLOW_EXP) * fl / ll;
                float ch_diss    = fabsf(c_diss * cq * fl);
                float sh_diss    = fabsf(c_diss * sq * CAV_SPACE * fl);

                float term = sheet_flux + chan_flux + ch_diss + sh_diss;
                s_col[cnt] = j; s_val[cnt] = -term; ++cnt;
                diag += term;
            }
            s_col[cnt] = i; s_val[cnt] = diag; ++cnt;
        }
        s_cnt = cnt;
    }
    __syncthreads();

    const int cnt = s_cnt;
    // Stream the row: N = 10000 is divisible by 4, rows are 16B-aligned.
    const int chunks = N >> 2;                    // float4 chunks per row
    float4* row4 = reinterpret_cast<float4*>(row);
    for (int c = threadIdx.x; c < chunks; c += blockDim.x) {
        float4 v = make_float4(0.0f, 0.0f, 0.0f, 0.0f);
        const int base = c << 2;
        for (int k = 0; k < cnt; ++k) {
            int d = s_col[k] - base;
            if ((unsigned)d < 4u) (&v.x)[d] = s_val[k];
        }
        row4[c] = v;
    }
    // Tail guard (not hit for N % 4 == 0, kept for generality)
    for (int c = (chunks << 2) + (int)threadIdx.x; c < N; c += blockDim.x) {
        float v = 0.0f;
        for (int k = 0; k < cnt; ++k) if (s_col[k] == c) v = s_val[k];
        row[c] = v;
    }
}

extern "C" void kernel_launch(void* const* d_in, const int* in_sizes, int n_in,
                              void* d_out, int out_size, void* d_ws, size_t ws_size,
                              hipStream_t stream) {
    const float* pot      = (const float*)d_in[0];   // previous_potential [N]
    const float* chan     = (const float*)d_in[1];   // channel_size [L]
    const float* sheet    = (const float*)d_in[2];   // sheet_thickness [N]
    const float* face_len = (const float*)d_in[3];   // length_of_face [L]
    const float* link_len = (const float*)d_in[4];   // length_of_link [L]
    const int*   adj      = (const int*)d_in[5];     // adjacent_nodes [N,4]
    const int*   lnk      = (const int*)d_in[6];     // links_at_node [N,4]
    const int*   fal      = (const int*)d_in[7];     // face_at_link [L]
    const int*   head     = (const int*)d_in[8];     // link_head [L]
    const int*   tail     = (const int*)d_in[9];     // link_tail [L]
    const int*   inout    = (const int*)d_in[10];    // inflow_outflow [N]

    float* M = (float*)d_out;
    int N = in_sizes[0];                             // 10000

    // One block per row: fused zero-fill + sparse patch, single pass over 400 MB.
    sgds_row_kernel<<<N, 256, 0, stream>>>(pot, chan, sheet, face_len, link_len,
                                           adj, lnk, fal, head, tail, inout, M, N);
}